// Round 1
// baseline (640.443 us; speedup 1.0000x reference)
//
#include <hip/hip_runtime.h>
#include <math.h>

#define NB 16
#define NH 512
#define NW 512
#define NHW (NH * NW)
#define LAMBDA 0.1f
#define TOLV 0.001f
#define MAXIT 10
#define RPB 4                 // rows per block
#define NCHUNK (NH / RPB)     // 128 chunks per batch
#define NTHREADS 256
#define PPT (RPB * NW / NTHREADS)  // 8 pixels per thread

// ws layout:
//   [0 .. NB*NCHUNK*5) doubles : per-block partial sums
//   then 32 floats  : current p
//   then 1 float    : current err
#define PARTIALS_DOUBLES (NB * NCHUNK * 5)
#define PWS_OFF_BYTES (PARTIALS_DOUBLES * 8)
#define ERR_OFF_BYTES (PWS_OFF_BYTES + 32 * 4)

__device__ __forceinline__ float cubicf(float t) {
    float a = fabsf(t);
    float a2 = a * a;
    float a3 = a2 * a;
    if (a <= 1.0f) return 1.5f * a3 - 2.5f * a2 + 1.0f;
    if (a < 2.0f)  return -0.5f * a3 + 2.5f * a2 - 4.0f * a + 2.0f;
    return 0.0f;
}

__device__ __forceinline__ float warp_pixel(const float* __restrict__ I2b,
                                            int y, int c, float tx, float ty) {
    float gx = (float)c + tx;
    float fx = floorf(gx);
    int   x0 = (int)fx;
    float dx = gx - fx;
    float gy = (float)y + ty;
    float fy = floorf(gy);
    int   y0 = (int)fy;
    float dy = gy - fy;

    float wx0 = cubicf(dx + 1.0f), wx1 = cubicf(dx);
    float wx2 = cubicf(dx - 1.0f), wx3 = cubicf(dx - 2.0f);
    float wy0 = cubicf(dy + 1.0f), wy1 = cubicf(dy);
    float wy2 = cubicf(dy - 1.0f), wy3 = cubicf(dy - 2.0f);

    int xi0 = min(max(x0 - 1, 0), NW - 1);
    int xi1 = min(max(x0    , 0), NW - 1);
    int xi2 = min(max(x0 + 1, 0), NW - 1);
    int xi3 = min(max(x0 + 2, 0), NW - 1);

    float wyj[4] = {wy0, wy1, wy2, wy3};
    float Iw = 0.0f;
#pragma unroll
    for (int j = 0; j < 4; ++j) {
        int yj = min(max(y0 - 1 + j, 0), NH - 1);
        const float* row = I2b + yj * NW;
        float h = wx0 * row[xi0] + wx1 * row[xi1] + wx2 * row[xi2] + wx3 * row[xi3];
        Iw += wyj[j] * h;
    }
    return Iw;
}

__global__ __launch_bounds__(NTHREADS) void gn_init(const float* __restrict__ p_in,
                                                    float* __restrict__ pws,
                                                    float* __restrict__ errws) {
    int t = threadIdx.x;
    if (t < 2 * NB) pws[t] = p_in[t];
    if (t == 0) errws[0] = 1e10f;
}

__global__ __launch_bounds__(NTHREADS) void gn_reduce(const float* __restrict__ I1,
                                                      const float* __restrict__ I2,
                                                      const float* __restrict__ pws,
                                                      double* __restrict__ partials) {
    const int b = blockIdx.y;
    const int chunk = blockIdx.x;
    const int tid = threadIdx.x;
    const float tx = pws[2 * b];
    const float ty = pws[2 * b + 1];
    const float* I1b = I1 + (size_t)b * NHW;
    const float* I2b = I2 + (size_t)b * NHW;

    double a0 = 0, a1 = 0, a2 = 0, a3 = 0, a4 = 0;

#pragma unroll
    for (int k = 0; k < PPT; ++k) {
        int idx = k * NTHREADS + tid;
        int r = idx >> 9;          // NW == 512
        int c = idx & (NW - 1);
        int y = chunk * RPB + r;

        float Iw = warp_pixel(I2b, y, c, tx, ty);
        float c1 = I1b[y * NW + c];
        float DI = Iw - c1;
        float rho = 1.0f / sqrtf(DI * DI + LAMBDA * LAMBDA);

        float Ix = (c >= 1 && c <= NW - 2)
                       ? 0.5f * (I1b[y * NW + c + 1] - I1b[y * NW + c - 1]) : 0.0f;
        float Iy = (y >= 1 && y <= NH - 2)
                       ? 0.5f * (I1b[(y + 1) * NW + c] - I1b[(y - 1) * NW + c]) : 0.0f;

        float dr = DI * rho;
        a0 += (double)(Ix * Ix * rho);
        a1 += (double)(Ix * Iy * rho);
        a2 += (double)(Iy * Iy * rho);
        a3 += (double)(Ix * dr);
        a4 += (double)(Iy * dr);
    }

    // wave (64-lane) shuffle reduction
#pragma unroll
    for (int off = 32; off > 0; off >>= 1) {
        a0 += __shfl_down(a0, off);
        a1 += __shfl_down(a1, off);
        a2 += __shfl_down(a2, off);
        a3 += __shfl_down(a3, off);
        a4 += __shfl_down(a4, off);
    }

    __shared__ double wsum[NTHREADS / 64][5];
    int wave = tid >> 6, lane = tid & 63;
    if (lane == 0) {
        wsum[wave][0] = a0; wsum[wave][1] = a1; wsum[wave][2] = a2;
        wsum[wave][3] = a3; wsum[wave][4] = a4;
    }
    __syncthreads();
    if (tid == 0) {
        double s0 = 0, s1 = 0, s2 = 0, s3 = 0, s4 = 0;
#pragma unroll
        for (int w = 0; w < NTHREADS / 64; ++w) {
            s0 += wsum[w][0]; s1 += wsum[w][1]; s2 += wsum[w][2];
            s3 += wsum[w][3]; s4 += wsum[w][4];
        }
        double* dst = partials + ((size_t)b * NCHUNK + chunk) * 5;
        dst[0] = s0; dst[1] = s1; dst[2] = s2; dst[3] = s3; dst[4] = s4;
    }
}

__global__ __launch_bounds__(128) void gn_update(const double* __restrict__ partials,
                                                 float* __restrict__ pws,
                                                 float* __restrict__ errws,
                                                 float* __restrict__ out,
                                                 int write_out) {
    __shared__ double Hs[NB][5];
    __shared__ float dpf[NB][2];
    __shared__ float pnew[2 * NB];
    const int tid = threadIdx.x;

    if (tid < NB * 5) {
        int b = tid / 5, comp = tid % 5;
        double s = 0;
        for (int ch = 0; ch < NCHUNK; ++ch)
            s += partials[((size_t)b * NCHUNK + ch) * 5 + comp];
        Hs[b][comp] = s;
    }
    __syncthreads();

    if (tid < NB) {
        double H00 = Hs[tid][0], H01 = Hs[tid][1], H11 = Hs[tid][2];
        double b0 = Hs[tid][3], b1 = Hs[tid][4];
        double inv = 1.0 / (H00 * H11 - H01 * H01);
        double dp0 = ( H11 * b0 - H01 * b1) * inv;
        double dp1 = (-H01 * b0 + H00 * b1) * inv;
        dpf[tid][0] = (float)dp0;
        dpf[tid][1] = (float)dp1;
    }
    __syncthreads();

    float err_old = errws[0];
    bool active = err_old > TOLV;

    if (tid < 2 * NB) {
        float pv = pws[tid];
        if (active) pv -= dpf[tid >> 1][tid & 1];
        pnew[tid] = pv;
        pws[tid] = pv;
    }

    float err_new = err_old;
    if (tid == 0) {
        if (active) {
            double n = 0;
            for (int i = 0; i < NB; ++i) {
                n += (double)dpf[i][0] * (double)dpf[i][0];
                n += (double)dpf[i][1] * (double)dpf[i][1];
            }
            err_new = (float)sqrt(n);
            errws[0] = err_new;
        }
    }
    __syncthreads();
    if (write_out) {
        if (tid < 2 * NB) out[tid] = pnew[tid];
        if (tid == 0) out[2 * NB] = err_new;
    }
}

__global__ __launch_bounds__(NTHREADS) void gn_final(const float* __restrict__ I1,
                                                     const float* __restrict__ I2,
                                                     const float* __restrict__ pws,
                                                     float* __restrict__ out) {
    const int b = blockIdx.y;
    const int chunk = blockIdx.x;
    const int tid = threadIdx.x;
    const float tx = pws[2 * b];
    const float ty = pws[2 * b + 1];
    const float* I1b = I1 + (size_t)b * NHW;
    const float* I2b = I2 + (size_t)b * NHW;

    float* DIout = out + 33;
    float* IWout = out + 33 + (size_t)NB * NHW;

#pragma unroll
    for (int k = 0; k < PPT; ++k) {
        int idx = k * NTHREADS + tid;
        int r = idx >> 9;
        int c = idx & (NW - 1);
        int y = chunk * RPB + r;

        float Iw = warp_pixel(I2b, y, c, tx, ty);
        float c1 = I1b[y * NW + c];
        size_t o = (size_t)b * NHW + (size_t)y * NW + c;
        DIout[o] = Iw - c1;
        IWout[o] = Iw;
    }
}

extern "C" void kernel_launch(void* const* d_in, const int* in_sizes, int n_in,
                              void* d_out, int out_size, void* d_ws, size_t ws_size,
                              hipStream_t stream) {
    const float* I1 = (const float*)d_in[0];
    const float* I2 = (const float*)d_in[1];
    const float* p  = (const float*)d_in[2];
    float* out = (float*)d_out;

    double* partials = (double*)d_ws;
    float* pws  = (float*)((char*)d_ws + PWS_OFF_BYTES);
    float* errws = (float*)((char*)d_ws + ERR_OFF_BYTES);

    gn_init<<<1, NTHREADS, 0, stream>>>(p, pws, errws);

    dim3 grid(NCHUNK, NB);
    for (int t = 0; t < MAXIT; ++t) {
        gn_reduce<<<grid, NTHREADS, 0, stream>>>(I1, I2, pws, partials);
        gn_update<<<1, 128, 0, stream>>>(partials, pws, errws, out, (t == MAXIT - 1) ? 1 : 0);
    }
    gn_final<<<grid, NTHREADS, 0, stream>>>(I1, I2, pws, out);
}

// Round 2
// 249.931 us; speedup vs baseline: 2.5625x; 2.5625x over previous
//
#include <hip/hip_runtime.h>
#include <math.h>

#define NB 16
#define NH 512
#define NW 512
#define NHW (NH * NW)
#define LAM2 0.01f
#define TOLV 0.001f
#define MAXIT 10
#define ROWS 8                  // rows per block strip
#define NCHUNK (NH / ROWS)      // 64 blocks per batch
#define NTHREADS 256

// ws layout:
//   [0 .. NB*NCHUNK*5) doubles : per-block partial sums
//   then 32 floats  : current p
//   then 1 float    : current err
#define PARTIALS_DOUBLES (NB * NCHUNK * 5)
#define PWS_OFF_BYTES (PARTIALS_DOUBLES * 8)
#define ERR_OFF_BYTES (PWS_OFF_BYTES + 32 * 4)

__device__ __forceinline__ float cubicf(float t) {
    float a = fabsf(t);
    float a2 = a * a;
    float a3 = a2 * a;
    if (a <= 1.0f) return 1.5f * a3 - 2.5f * a2 + 1.0f;
    if (a < 2.0f)  return -0.5f * a3 + 2.5f * a2 - 4.0f * a + 2.0f;
    return 0.0f;
}

// Per-column bicubic weights + clamped tap indices, bit-identical to reference
__device__ __forceinline__ void col_setup(int c, float tx, float* wx, int* xi) {
    float gx = (float)c + tx;
    float fx = floorf(gx);
    int x0 = (int)fx;
    float dx = gx - fx;
    wx[0] = cubicf(dx + 1.0f);
    wx[1] = cubicf(dx);
    wx[2] = cubicf(dx - 1.0f);
    wx[3] = cubicf(dx - 2.0f);
#pragma unroll
    for (int i = 0; i < 4; ++i) xi[i] = min(max(x0 - 1 + i, 0), NW - 1);
}

__global__ __launch_bounds__(NTHREADS) void gn_init(const float* __restrict__ p_in,
                                                    float* __restrict__ pws,
                                                    float* __restrict__ errws) {
    int t = threadIdx.x;
    if (t < 2 * NB) pws[t] = p_in[t];
    if (t == 0) errws[0] = 1e10f;
}

__global__ __launch_bounds__(NTHREADS) void gn_reduce(const float* __restrict__ I1,
                                                      const float* __restrict__ I2,
                                                      const float* __restrict__ pws,
                                                      double* __restrict__ partials) {
    const int b = blockIdx.y;
    const int strip = blockIdx.x;
    const int tid = threadIdx.x;
    const float tx = pws[2 * b];
    const float ty = pws[2 * b + 1];
    const float* I1b = I1 + (size_t)b * NHW;
    const float* I2b = I2 + (size_t)b * NHW;

    const int cA = 2 * tid;
    const int cB = 2 * tid + 1;
    float wxA[4], wxB[4];
    int xiA[4], xiB[4];
    col_setup(cA, tx, wxA, xiA);
    col_setup(cB, tx, wxB, xiB);

    __shared__ float wyS[ROWS][4];
    __shared__ int   yjS[ROWS][4];
    __shared__ float V[2][NW];

    if (tid < ROWS) {
        int y = strip * ROWS + tid;
        float gy = (float)y + ty;
        float fy = floorf(gy);
        int y0 = (int)fy;
        float dy = gy - fy;
        wyS[tid][0] = cubicf(dy + 1.0f);
        wyS[tid][1] = cubicf(dy);
        wyS[tid][2] = cubicf(dy - 1.0f);
        wyS[tid][3] = cubicf(dy - 2.0f);
#pragma unroll
        for (int i = 0; i < 4; ++i) yjS[tid][i] = min(max(y0 - 1 + i, 0), NH - 1);
    }
    __syncthreads();

    double a0 = 0, a1 = 0, a2 = 0, a3 = 0, a4 = 0;

    for (int r = 0; r < ROWS; ++r) {
        const int y = strip * ROWS + r;
        const float wy0 = wyS[r][0], wy1 = wyS[r][1], wy2 = wyS[r][2], wy3 = wyS[r][3];
        const float2* r0 = (const float2*)(I2b + (size_t)yjS[r][0] * NW);
        const float2* r1 = (const float2*)(I2b + (size_t)yjS[r][1] * NW);
        const float2* r2 = (const float2*)(I2b + (size_t)yjS[r][2] * NW);
        const float2* r3 = (const float2*)(I2b + (size_t)yjS[r][3] * NW);
        float2 p0 = r0[tid], p1 = r1[tid], p2 = r2[tid], p3 = r3[tid];
        float* Vb = V[r & 1];
        Vb[cA] = wy0 * p0.x + wy1 * p1.x + wy2 * p2.x + wy3 * p3.x;
        Vb[cB] = wy0 * p0.y + wy1 * p1.y + wy2 * p2.y + wy3 * p3.y;
        __syncthreads();

        const float* I1r = I1b + (size_t)y * NW;
        float2 cc = *(const float2*)(I1r + cA);
        float left  = (tid > 0) ? I1r[cA - 1] : 0.0f;
        float right = (tid < NTHREADS - 1) ? I1r[cB + 1] : 0.0f;
        float IxA = (cA >= 1) ? 0.5f * (cc.y - left) : 0.0f;
        float IxB = (cB <= NW - 2) ? 0.5f * (right - cc.x) : 0.0f;
        float IyA = 0.0f, IyB = 0.0f;
        if (y >= 1 && y <= NH - 2) {
            float2 up = *(const float2*)(I1b + (size_t)(y - 1) * NW + cA);
            float2 dn = *(const float2*)(I1b + (size_t)(y + 1) * NW + cA);
            IyA = 0.5f * (dn.x - up.x);
            IyB = 0.5f * (dn.y - up.y);
        }

        float IwA = wxA[0] * Vb[xiA[0]] + wxA[1] * Vb[xiA[1]] +
                    wxA[2] * Vb[xiA[2]] + wxA[3] * Vb[xiA[3]];
        float IwB = wxB[0] * Vb[xiB[0]] + wxB[1] * Vb[xiB[1]] +
                    wxB[2] * Vb[xiB[2]] + wxB[3] * Vb[xiB[3]];

        float DIA = IwA - cc.x, DIB = IwB - cc.y;
        float rhoA = 1.0f / sqrtf(DIA * DIA + LAM2);
        float rhoB = 1.0f / sqrtf(DIB * DIB + LAM2);
        float drA = DIA * rhoA, drB = DIB * rhoB;

        a0 += (double)(IxA * IxA * rhoA) + (double)(IxB * IxB * rhoB);
        a1 += (double)(IxA * IyA * rhoA) + (double)(IxB * IyB * rhoB);
        a2 += (double)(IyA * IyA * rhoA) + (double)(IyB * IyB * rhoB);
        a3 += (double)(IxA * drA) + (double)(IxB * drB);
        a4 += (double)(IyA * drA) + (double)(IyB * drB);
        // no second sync needed: V is double-buffered; writes to this buffer
        // recur only after the NEXT row's barrier.
    }

#pragma unroll
    for (int off = 32; off > 0; off >>= 1) {
        a0 += __shfl_down(a0, off);
        a1 += __shfl_down(a1, off);
        a2 += __shfl_down(a2, off);
        a3 += __shfl_down(a3, off);
        a4 += __shfl_down(a4, off);
    }

    __shared__ double wsum[NTHREADS / 64][5];
    int wave = tid >> 6, lane = tid & 63;
    if (lane == 0) {
        wsum[wave][0] = a0; wsum[wave][1] = a1; wsum[wave][2] = a2;
        wsum[wave][3] = a3; wsum[wave][4] = a4;
    }
    __syncthreads();
    if (tid == 0) {
        double s0 = 0, s1 = 0, s2 = 0, s3 = 0, s4 = 0;
#pragma unroll
        for (int w = 0; w < NTHREADS / 64; ++w) {
            s0 += wsum[w][0]; s1 += wsum[w][1]; s2 += wsum[w][2];
            s3 += wsum[w][3]; s4 += wsum[w][4];
        }
        double* dst = partials + ((size_t)b * NCHUNK + strip) * 5;
        dst[0] = s0; dst[1] = s1; dst[2] = s2; dst[3] = s3; dst[4] = s4;
    }
}

__global__ __launch_bounds__(128) void gn_update(const double* __restrict__ partials,
                                                 float* __restrict__ pws,
                                                 float* __restrict__ errws,
                                                 float* __restrict__ out,
                                                 int write_out) {
    __shared__ double Hs[NB][5];
    __shared__ float dpf[NB][2];
    __shared__ float pnew[2 * NB];
    const int tid = threadIdx.x;

    if (tid < NB * 5) {
        int b = tid / 5, comp = tid % 5;
        double s = 0;
        for (int ch = 0; ch < NCHUNK; ++ch)
            s += partials[((size_t)b * NCHUNK + ch) * 5 + comp];
        Hs[b][comp] = s;
    }
    __syncthreads();

    if (tid < NB) {
        double H00 = Hs[tid][0], H01 = Hs[tid][1], H11 = Hs[tid][2];
        double b0 = Hs[tid][3], b1 = Hs[tid][4];
        double inv = 1.0 / (H00 * H11 - H01 * H01);
        double dp0 = ( H11 * b0 - H01 * b1) * inv;
        double dp1 = (-H01 * b0 + H00 * b1) * inv;
        dpf[tid][0] = (float)dp0;
        dpf[tid][1] = (float)dp1;
    }
    __syncthreads();

    float err_old = errws[0];
    bool active = err_old > TOLV;

    if (tid < 2 * NB) {
        float pv = pws[tid];
        if (active) pv -= dpf[tid >> 1][tid & 1];
        pnew[tid] = pv;
        pws[tid] = pv;
    }

    float err_new = err_old;
    if (tid == 0) {
        if (active) {
            double n = 0;
            for (int i = 0; i < NB; ++i) {
                n += (double)dpf[i][0] * (double)dpf[i][0];
                n += (double)dpf[i][1] * (double)dpf[i][1];
            }
            err_new = (float)sqrt(n);
            errws[0] = err_new;
        }
    }
    __syncthreads();
    if (write_out) {
        if (tid < 2 * NB) out[tid] = pnew[tid];
        if (tid == 0) out[2 * NB] = err_new;
    }
}

__global__ __launch_bounds__(NTHREADS) void gn_final(const float* __restrict__ I1,
                                                     const float* __restrict__ I2,
                                                     const float* __restrict__ pws,
                                                     float* __restrict__ out) {
    const int b = blockIdx.y;
    const int strip = blockIdx.x;
    const int tid = threadIdx.x;
    const float tx = pws[2 * b];
    const float ty = pws[2 * b + 1];
    const float* I1b = I1 + (size_t)b * NHW;
    const float* I2b = I2 + (size_t)b * NHW;

    float* DIout = out + 33;
    float* IWout = out + 33 + (size_t)NB * NHW;

    const int cA = 2 * tid;
    const int cB = 2 * tid + 1;
    float wxA[4], wxB[4];
    int xiA[4], xiB[4];
    col_setup(cA, tx, wxA, xiA);
    col_setup(cB, tx, wxB, xiB);

    __shared__ float wyS[ROWS][4];
    __shared__ int   yjS[ROWS][4];
    __shared__ float V[2][NW];

    if (tid < ROWS) {
        int y = strip * ROWS + tid;
        float gy = (float)y + ty;
        float fy = floorf(gy);
        int y0 = (int)fy;
        float dy = gy - fy;
        wyS[tid][0] = cubicf(dy + 1.0f);
        wyS[tid][1] = cubicf(dy);
        wyS[tid][2] = cubicf(dy - 1.0f);
        wyS[tid][3] = cubicf(dy - 2.0f);
#pragma unroll
        for (int i = 0; i < 4; ++i) yjS[tid][i] = min(max(y0 - 1 + i, 0), NH - 1);
    }
    __syncthreads();

    for (int r = 0; r < ROWS; ++r) {
        const int y = strip * ROWS + r;
        const float wy0 = wyS[r][0], wy1 = wyS[r][1], wy2 = wyS[r][2], wy3 = wyS[r][3];
        const float2* r0 = (const float2*)(I2b + (size_t)yjS[r][0] * NW);
        const float2* r1 = (const float2*)(I2b + (size_t)yjS[r][1] * NW);
        const float2* r2 = (const float2*)(I2b + (size_t)yjS[r][2] * NW);
        const float2* r3 = (const float2*)(I2b + (size_t)yjS[r][3] * NW);
        float2 p0 = r0[tid], p1 = r1[tid], p2 = r2[tid], p3 = r3[tid];
        float* Vb = V[r & 1];
        Vb[cA] = wy0 * p0.x + wy1 * p1.x + wy2 * p2.x + wy3 * p3.x;
        Vb[cB] = wy0 * p0.y + wy1 * p1.y + wy2 * p2.y + wy3 * p3.y;
        __syncthreads();

        const float* I1r = I1b + (size_t)y * NW;
        float2 cc = *(const float2*)(I1r + cA);

        float IwA = wxA[0] * Vb[xiA[0]] + wxA[1] * Vb[xiA[1]] +
                    wxA[2] * Vb[xiA[2]] + wxA[3] * Vb[xiA[3]];
        float IwB = wxB[0] * Vb[xiB[0]] + wxB[1] * Vb[xiB[1]] +
                    wxB[2] * Vb[xiB[2]] + wxB[3] * Vb[xiB[3]];

        size_t o = (size_t)b * NHW + (size_t)y * NW + cA;
        DIout[o]     = IwA - cc.x;
        DIout[o + 1] = IwB - cc.y;
        IWout[o]     = IwA;
        IWout[o + 1] = IwB;
    }
}

extern "C" void kernel_launch(void* const* d_in, const int* in_sizes, int n_in,
                              void* d_out, int out_size, void* d_ws, size_t ws_size,
                              hipStream_t stream) {
    const float* I1 = (const float*)d_in[0];
    const float* I2 = (const float*)d_in[1];
    const float* p  = (const float*)d_in[2];
    float* out = (float*)d_out;

    double* partials = (double*)d_ws;
    float* pws  = (float*)((char*)d_ws + PWS_OFF_BYTES);
    float* errws = (float*)((char*)d_ws + ERR_OFF_BYTES);

    gn_init<<<1, NTHREADS, 0, stream>>>(p, pws, errws);

    dim3 grid(NCHUNK, NB);
    for (int t = 0; t < MAXIT; ++t) {
        gn_reduce<<<grid, NTHREADS, 0, stream>>>(I1, I2, pws, partials);
        gn_update<<<1, 128, 0, stream>>>(partials, pws, errws, out, (t == MAXIT - 1) ? 1 : 0);
    }
    gn_final<<<grid, NTHREADS, 0, stream>>>(I1, I2, pws, out);
}